// Round 3
// baseline (696.559 us; speedup 1.0000x reference)
//
#include <hip/hip_runtime.h>
#include <hip/hip_bf16.h>

constexpr int B  = 8;
constexpr int LQ = 2048;
constexpr int LK = 4096;
constexpr int C  = 1024;
constexpr int H  = 16;
constexpr int D  = 64;
constexpr int CS = 8;
constexpr int KC = 256;
constexpr int GRID = 512;   // 2 blocks/CU guaranteed resident (see launch_bounds)
constexpr float SCALE = 0.125f;

typedef __attribute__((ext_vector_type(8))) short short8;
typedef __attribute__((ext_vector_type(4))) float f32x4;

union FragU { unsigned u[4]; short8 s; float4 f; };

__device__ inline unsigned bfp(float a, float b) {
  float2 f2; f2.x = a; f2.y = b;
  __hip_bfloat162 h = __float22bfloat162_rn(f2); // v_cvt_pk_bf16_f32
  return *reinterpret_cast<unsigned*>(&h);
}

// ---------------------------------------------------------------------------
// Generation barrier: bar[0]=arrive count, bar[1]=generation. Device-scope
// atomics (cross-XCD coherent); release/acquire through the atomic pair plus
// __threadfence covers the non-atomic data handoff. Bounded spin: a broken
// residency assumption produces a finite wrong answer, never a harness hang.
// ---------------------------------------------------------------------------
__device__ inline void gridbar(int* bar) {
  __syncthreads();
  if (threadIdx.x == 0) {
    __threadfence();
    const int g = __hip_atomic_load(bar + 1, __ATOMIC_RELAXED, __HIP_MEMORY_SCOPE_AGENT);
    const int a = __hip_atomic_fetch_add(bar, 1, __ATOMIC_ACQ_REL, __HIP_MEMORY_SCOPE_AGENT);
    if (a == GRID - 1) {
      __hip_atomic_store(bar, 0, __ATOMIC_RELAXED, __HIP_MEMORY_SCOPE_AGENT);
      __hip_atomic_fetch_add(bar + 1, 1, __ATOMIC_RELEASE, __HIP_MEMORY_SCOPE_AGENT);
    } else {
      int it = 0;
      while (__hip_atomic_load(bar + 1, __ATOMIC_ACQUIRE, __HIP_MEMORY_SCOPE_AGENT) == g) {
        if (++it > 2000000) break;
        __builtin_amdgcn_s_sleep(8);
      }
    }
    __threadfence();
  }
  __syncthreads();
}

// ---------------------------------------------------------------------------
// Init: zero per-batch histogram + barrier state (workspace is poisoned).
// ---------------------------------------------------------------------------
__global__ __launch_bounds__(256) void k_init(int* __restrict__ histg,
                                              int* __restrict__ bar)
{
  const int i = blockIdx.x * 256 + threadIdx.x;
  if (i < B * KC) histg[i] = 0;
  if (i == 0) { bar[0] = 0; bar[1] = 0; }
}

// ---------------------------------------------------------------------------
// Fused pipeline (persistent kernel, 3 grid barriers):
//  A: bucket codes (fp32-exact) + global histogram
//  B: per-batch scan -> offsets + permutation + counts fragment tile
//  D: bucket gather-sum of v + direct MFMA B-fragment writes (coalesced)
//  E: bucketed attention (MFMA), XCD-affine tile assignment
// ---------------------------------------------------------------------------
__global__ __launch_bounds__(256, 2) void k_fused(
    const float* __restrict__ q, const float* __restrict__ kmat,
    const float* __restrict__ v, const float* __restrict__ Wc,
    const float* __restrict__ bc, const float* __restrict__ cb,
    float* __restrict__ out,
    int* __restrict__ idx, int* __restrict__ histg,
    int* __restrict__ offs, int* __restrict__ cnti, int* __restrict__ perm,
    float4* __restrict__ vfc, float4* __restrict__ vfb,
    int* __restrict__ bar)
{
  __shared__ __align__(16) char smem[32768];
  const int tid = threadIdx.x;
  const int lane = tid & 63, wave = tid >> 6;

  // ---------------- Phase A: codes + histogram ----------------
  {
    float* wS = (float*)smem; // 32 KB: Wc staged
    const float4* wsrc = (const float4*)Wc;
    float4* wdst = (float4*)wS;
#pragma unroll
    for (int i = 0; i < 8; ++i) wdst[tid + i * 256] = wsrc[tid + i * 256];
    float bcr[CS];
#pragma unroll
    for (int j = 0; j < CS; ++j) bcr[j] = bc[j];
    __syncthreads();

    for (int chunk = blockIdx.x; chunk < (B * LK) / 16; chunk += GRID) {
      for (int i = 0; i < 4; ++i) {
        const int r = chunk * 16 + wave * 4 + i;
        const float4* krow = (const float4*)(kmat + (size_t)r * C);
        float acc[CS];
#pragma unroll
        for (int j = 0; j < CS; ++j) acc[j] = 0.f;
#pragma unroll
        for (int rep = 0; rep < 4; ++rep) {
          float4 kv = krow[rep * 64 + lane];
          const int dbase = (rep * 64 + lane) * 4;
#pragma unroll
          for (int j = 0; j < CS; ++j) {
            float4 wv = *(const float4*)&wS[j * C + dbase];
            acc[j] += kv.x * wv.x + kv.y * wv.y + kv.z * wv.z + kv.w * wv.w;
          }
        }
#pragma unroll
        for (int j = 0; j < CS; ++j) {
#pragma unroll
          for (int off = 32; off >= 1; off >>= 1)
            acc[j] += __shfl_xor(acc[j], off, 64);
        }
        if (lane == 0) {
          int ix = 0;
#pragma unroll
          for (int j = 0; j < CS; ++j)
            ix |= ((acc[j] + bcr[j]) >= 0.f ? 1 : 0) << (7 - j);
          idx[r] = ix;
          atomicAdd(&histg[(r >> 12) * KC + ix], 1);
        }
      }
    }
  }
  gridbar(bar);

  // ---------------- Phase B: scan + permute + counts tile ----------------
  if (blockIdx.x < B) {
    int* idxS = (int*)smem;             // 16 KB
    int* cur  = (int*)(smem + 16384);   // 1 KB
    int* wsum = (int*)(smem + 17408);
    const int b = blockIdx.x;
    for (int i = tid; i < LK; i += 256) idxS[i] = idx[b * LK + i];
    const int myc = histg[b * KC + tid];
    int scan = myc;
#pragma unroll
    for (int off = 1; off < 64; off <<= 1) {
      int u = __shfl_up(scan, off, 64);
      if (lane >= off) scan += u;
    }
    if (lane == 63) wsum[wave] = scan;
    __syncthreads();
    int base = 0;
#pragma unroll
    for (int i = 0; i < 4; ++i) base += (i < wave) ? wsum[i] : 0;
    const int start = b * LK + base + scan - myc;
    offs[b * KC + tid] = start;
    cnti[b * KC + tid] = myc;
    cur[tid] = start;
    __syncthreads();
    for (int i = tid; i < LK; i += 256) {
      const int pos = atomicAdd(&cur[idxS[i]], 1);
      perm[pos] = b * LK + i;
    }
    for (int i = tid; i < 512; i += 256) {
      const int qc = i >> 6, ln = i & 63;
      FragU u4;
      if ((ln & 15) == 0) {
        const int* cs = histg + b * KC + (qc * 4 + (ln >> 4)) * 8;
        u4.u[0] = bfp((float)cs[0], (float)cs[1]);
        u4.u[1] = bfp((float)cs[2], (float)cs[3]);
        u4.u[2] = bfp((float)cs[4], (float)cs[5]);
        u4.u[3] = bfp((float)cs[6], (float)cs[7]);
      } else {
        u4.u[0] = u4.u[1] = u4.u[2] = u4.u[3] = 0u;
      }
      vfc[b * 512 + i] = u4.f;
    }
  }
  gridbar(bar);

  // ---------------- Phase D: gather-sum + fragment pack ----------------
  // Task td: batch b, bucket group o (8 buckets = the 8 shorts of a slot),
  // column half s. Thread owns cols {c0, c0+1} -> 2 consecutive float4
  // slots (32 B contiguous per thread, 512 B runs per 16 threads).
  for (int td = blockIdx.x; td < 512; td += GRID) {
    const int s = td & 1, o = (td >> 1) & 31, b = td >> 6;
    const int c0 = s * 512 + tid * 2;
    float2 acc[8];
#pragma unroll
    for (int j = 0; j < 8; ++j) { acc[j].x = 0.f; acc[j].y = 0.f; }
#pragma unroll
    for (int j = 0; j < 8; ++j) {
      const int bu = b * KC + o * 8 + j;
      const int st = offs[bu], cn = cnti[bu];
      int i = 0;
      for (; i + 4 <= cn; i += 4) {
        const int r0 = perm[st + i],     r1 = perm[st + i + 1];
        const int r2 = perm[st + i + 2], r3 = perm[st + i + 3];
        const float2 a = *(const float2*)(v + (size_t)r0 * C + c0);
        const float2 e = *(const float2*)(v + (size_t)r1 * C + c0);
        const float2 f = *(const float2*)(v + (size_t)r2 * C + c0);
        const float2 g = *(const float2*)(v + (size_t)r3 * C + c0);
        acc[j].x += a.x + e.x + f.x + g.x;
        acc[j].y += a.y + e.y + f.y + g.y;
      }
      for (; i < cn; ++i) {
        const int r0 = perm[st + i];
        const float2 a = *(const float2*)(v + (size_t)r0 * C + c0);
        acc[j].x += a.x; acc[j].y += a.y;
      }
    }
    const int h = c0 >> 6, n = c0 & 63;
    const int slot = ((o >> 2) * 4 + (n >> 4)) * 64 + (o & 3) * 16 + (n & 15);
    FragU lo, hi;
    lo.u[0] = bfp(acc[0].x, acc[1].x); lo.u[1] = bfp(acc[2].x, acc[3].x);
    lo.u[2] = bfp(acc[4].x, acc[5].x); lo.u[3] = bfp(acc[6].x, acc[7].x);
    hi.u[0] = bfp(acc[0].y, acc[1].y); hi.u[1] = bfp(acc[2].y, acc[3].y);
    hi.u[2] = bfp(acc[4].y, acc[5].y); hi.u[3] = bfp(acc[6].y, acc[7].y);
    float4* op = vfb + (size_t)(b * 16 + h) * 2048 + slot;
    op[0] = lo.f;   // col c0   (even)
    op[1] = hi.f;   // col c0+1
  }
  gridbar(bar);

  // ---------------- Phase E: attention ----------------
  {
    float4* QA  = (float4*)smem;            // 16 KB
    float4* CBf = (float4*)(smem + 16384);  // 2 KB
    float*  TS  = (float*)smem;             // alias over QA after t-MFMA
    const int wq = wave, quad = lane >> 4;
    const int xcd = blockIdx.x & 7, p = blockIdx.x >> 3;
    constexpr int PB = GRID >> 3;           // 64 blocks per xcd slot

    for (int ti = p; ti < 256; ti += PB) {
      const int b = xcd;                 // batch == XCD slot: vfb 512 KB / L2
      const int h = (ti >> 4) & 15;
      const int q0 = (ti & 15) * 128;

#pragma unroll
      for (int it = 0; it < 4; ++it) {
        const int od = tid & 7, m = it * 32 + (tid >> 3);
        const float* src = q + (size_t)(b * LQ + q0 + m) * C + h * D + od * 8;
        float4 f0 = *(const float4*)src, f1 = *(const float4*)(src + 4);
        FragU u;
        u.u[0] = bfp(f0.x * SCALE, f0.y * SCALE);
        u.u[1] = bfp(f0.z * SCALE, f0.w * SCALE);
        u.u[2] = bfp(f1.x * SCALE, f1.y * SCALE);
        u.u[3] = bfp(f1.z * SCALE, f1.w * SCALE);
        QA[((m >> 4) * 2 + (od >> 2)) * 64 + (od & 3) * 16 + (m & 15)] = u.f;
      }
      if (tid < 128) {
        const int od = tid & 7, j = tid >> 3;
        const float* src = cb + (size_t)j * C + h * D + od * 8;
        float4 f0 = *(const float4*)src, f1 = *(const float4*)(src + 4);
        FragU u;
        u.u[0] = bfp(f0.x, f0.y); u.u[1] = bfp(f0.z, f0.w);
        u.u[2] = bfp(f1.x, f1.y); u.u[3] = bfp(f1.z, f1.w);
        CBf[(od >> 2) * 64 + (od & 3) * 16 + j] = u.f;
      }
      __syncthreads();

      f32x4 tacc[2];
#pragma unroll
      for (int mt2 = 0; mt2 < 2; ++mt2) {
        const int mt = wq * 2 + mt2;
        FragU a0, a1, b0, b1;
        a0.f = QA[(mt * 2 + 0) * 64 + lane];
        a1.f = QA[(mt * 2 + 1) * 64 + lane];
        b0.f = CBf[0 * 64 + lane];
        b1.f = CBf[1 * 64 + lane];
        f32x4 z = {0.f, 0.f, 0.f, 0.f};
        z = __builtin_amdgcn_mfma_f32_16x16x32_bf16(a0.s, b0.s, z, 0, 0, 0);
        z = __builtin_amdgcn_mfma_f32_16x16x32_bf16(a1.s, b1.s, z, 0, 0, 0);
        tacc[mt2] = z;
      }
      __syncthreads();

#pragma unroll
      for (int mt2 = 0; mt2 < 2; ++mt2) {
        const int mt = wq * 2 + mt2;
#pragma unroll
        for (int r = 0; r < 4; ++r)
          TS[mt * 272 + (quad * 4 + r) * 17 + (lane & 15)] = tacc[mt2][r];
      }
      __syncthreads();
      float t0[16], t1[16];
#pragma unroll
      for (int j = 0; j < 16; ++j) {
        t0[j] = TS[(wq * 2 + 0) * 272 + (lane & 15) * 17 + j];
        t1[j] = TS[(wq * 2 + 1) * 272 + (lane & 15) * 17 + j];
      }

      float esl0[8], esl1[8];
#pragma unroll
      for (int c = 0; c < 8; ++c) {
        esl0[c] = __expf(((c & 4) ? t0[5] : t0[13]) + ((c & 2) ? t0[6] : t0[14]) +
                         ((c & 1) ? t0[7] : t0[15]));
        esl1[c] = __expf(((c & 4) ? t1[5] : t1[13]) + ((c & 2) ? t1[6] : t1[14]) +
                         ((c & 1) ? t1[7] : t1[15]));
      }

      f32x4 acc[2][5];
#pragma unroll
      for (int i = 0; i < 2; ++i)
#pragma unroll
        for (int t_ = 0; t_ < 5; ++t_) acc[i][t_] = (f32x4){0.f, 0.f, 0.f, 0.f};

      const float4* vb = vfb + (size_t)(b * 16 + h) * 2048 + lane;
      const float4* vc = vfc + b * 512 + lane;

#pragma unroll
      for (int qc = 0; qc < 8; ++qc) {
        FragU bf0, bf1_, bf2, bf3, cf;
        bf0.f = vb[(qc * 4 + 0) * 64];
        bf1_.f = vb[(qc * 4 + 1) * 64];
        bf2.f = vb[(qc * 4 + 2) * 64];
        bf3.f = vb[(qc * 4 + 3) * 64];
        cf.f  = vc[qc * 64];

        const int u = qc * 4 + quad;
        const float eshi0 = __expf(
            ((u & 16) ? t0[0] : t0[8]) + ((u & 8) ? t0[1] : t0[9]) +
            ((u & 4) ? t0[2] : t0[10]) + ((u & 2) ? t0[3] : t0[11]) +
            ((u & 1) ? t0[4] : t0[12]));
        const float eshi1 = __expf(
            ((u & 16) ? t1[0] : t1[8]) + ((u & 8) ? t1[1] : t1[9]) +
            ((u & 4) ? t1[2] : t1[10]) + ((u & 2) ? t1[3] : t1[11]) +
            ((u & 1) ? t1[4] : t1[12]));

        FragU a0, a1;
        a0.u[0] = bfp(eshi0 * esl0[0], eshi0 * esl0[1]);
        a0.u[1] = bfp(eshi0 * esl0[2], eshi0 * esl0[3]);
        a0.u[2] = bfp(eshi0 * esl0[4], eshi0 * esl0[5]);
        a0.u[3] = bfp(eshi0 * esl0[6], eshi0 * esl0[7]);
        a1.u[0] = bfp(eshi1 * esl1[0], eshi1 * esl1[1]);
        a1.u[1] = bfp(eshi1 * esl1[2], eshi1 * esl1[3]);
        a1.u[2] = bfp(eshi1 * esl1[4], eshi1 * esl1[5]);
        a1.u[3] = bfp(eshi1 * esl1[6], eshi1 * esl1[7]);

        acc[0][0] = __builtin_amdgcn_mfma_f32_16x16x32_bf16(a0.s, bf0.s,  acc[0][0], 0, 0, 0);
        acc[1][0] = __builtin_amdgcn_mfma_f32_16x16x32_bf16(a1.s, bf0.s,  acc[1][0], 0, 0, 0);
        acc[0][1] = __builtin_amdgcn_mfma_f32_16x16x32_bf16(a0.s, bf1_.s, acc[0][1], 0, 0, 0);
        acc[1][1] = __builtin_amdgcn_mfma_f32_16x16x32_bf16(a1.s, bf1_.s, acc[1][1], 0, 0, 0);
        acc[0][2] = __builtin_amdgcn_mfma_f32_16x16x32_bf16(a0.s, bf2.s,  acc[0][2], 0, 0, 0);
        acc[1][2] = __builtin_amdgcn_mfma_f32_16x16x32_bf16(a1.s, bf2.s,  acc[1][2], 0, 0, 0);
        acc[0][3] = __builtin_amdgcn_mfma_f32_16x16x32_bf16(a0.s, bf3.s,  acc[0][3], 0, 0, 0);
        acc[1][3] = __builtin_amdgcn_mfma_f32_16x16x32_bf16(a1.s, bf3.s,  acc[1][3], 0, 0, 0);
        acc[0][4] = __builtin_amdgcn_mfma_f32_16x16x32_bf16(a0.s, cf.s,   acc[0][4], 0, 0, 0);
        acc[1][4] = __builtin_amdgcn_mfma_f32_16x16x32_bf16(a1.s, cf.s,   acc[1][4], 0, 0, 0);
      }

      const int srcl = lane & 48;
#pragma unroll
      for (int mt2 = 0; mt2 < 2; ++mt2) {
#pragma unroll
        for (int r = 0; r < 4; ++r) {
          const float den = __shfl(acc[mt2][4][r], srcl, 64);
          const float inv = 1.0f / den;
          const int row = q0 + wq * 32 + mt2 * 16 + quad * 4 + r;
          float* op = out + (size_t)(b * LQ + row) * C + h * D + (lane & 15);
#pragma unroll
          for (int t_ = 0; t_ < 4; ++t_)
            __builtin_nontemporal_store(acc[mt2][t_][r] * inv, op + t_ * 16);
        }
      }
      __syncthreads();  // protect QA/TS reuse before next tile
    }
  }
}

// ---------------------------------------------------------------------------
extern "C" void kernel_launch(void* const* d_in, const int* in_sizes, int n_in,
                              void* d_out, int out_size, void* d_ws, size_t ws_size,
                              hipStream_t stream) {
  (void)in_sizes; (void)n_in; (void)out_size; (void)ws_size;
  const float* q  = (const float*)d_in[0];
  const float* k  = (const float*)d_in[1];
  const float* v  = (const float*)d_in[2];
  const float* Wc = (const float*)d_in[3];
  const float* bc = (const float*)d_in[4];
  const float* cb = (const float*)d_in[5];
  float* out = (float*)d_out;

  char* ws = (char*)d_ws;
  int*    idxp  = (int*)ws;                      // 128 KB
  int*    histp = (int*)(ws + 0x20000);          // 8 KB
  int*    offsp = (int*)(ws + 0x22000);          // 8 KB
  int*    cntip = (int*)(ws + 0x24000);          // 8 KB
  int*    permp = (int*)(ws + 0x26000);          // 128 KB
  float4* vfcp  = (float4*)(ws + 0x46000);       // 64 KB
  int*    barp  = (int*)(ws + 0x56000);          // barrier state
  float4* vfbp  = (float4*)(ws + 0x60000);       // 4 MB

  hipLaunchKernelGGL(k_init, dim3(8), dim3(256), 0, stream, histp, barp);
  hipLaunchKernelGGL(k_fused, dim3(GRID), dim3(256), 0, stream,
                     q, k, v, Wc, bc, cb, out,
                     idxp, histp, offsp, cntip, permp, vfcp, vfbp, barp);
}